// Round 3
// baseline (1651.150 us; speedup 1.0000x reference)
//
#include <hip/hip_runtime.h>
#include <math.h>

// ---------------------------------------------------------------------------
// Round 5: (a) head GEMM XCD-chunked swizzle (W-tile sharers land on one XCD's
// L2: FETCH 268MB -> ~90MB); (b) barrier-free attention - K/V are L2-resident
// (256KB/head) so MFMA fragments load directly from global, no LDS staging,
// no __syncthreads, XCD-swizzled for KV L2 locality; (c) fp32 transcendentals
// in embed_pe (was f64); (d) per-layer weight f2bf merged 6 launches -> 1.
// ---------------------------------------------------------------------------

namespace {
constexpr int kV  = 32000;
constexpr int kD  = 1024;
constexpr int kH  = 16;
constexpr int kL  = 4;
constexpr int kF  = 4096;
constexpr int kS  = 1024;
constexpr int kB  = 2;
constexpr int kDK = 64;
constexpr int kM  = kB * kS;   // 2048 rows
constexpr float kEps   = 1e-5f;
constexpr float kScale = 0.125f;   // 1/sqrt(DK)
}

using short8 = __attribute__((ext_vector_type(8))) short;
using f32x4  = __attribute__((ext_vector_type(4))) float;

__device__ __forceinline__ unsigned short f2bf(float f) {
  union { float f; unsigned int u; } x{f};
  const unsigned int r = x.u + 0x7fffu + ((x.u >> 16) & 1u);
  return (unsigned short)(r >> 16);
}

// async 16B global -> LDS (lds base must be wave-uniform; lane scatters +16B)
__device__ __forceinline__ void llds16(const void* g, void* l) {
  __builtin_amdgcn_global_load_lds(
      (const __attribute__((address_space(1))) unsigned int*)g,
      (__attribute__((address_space(3))) unsigned int*)l, 16, 0, 0);
}

// ---- block reductions (blockDim.x == 256 -> 4 waves of 64) ----------------
__device__ __forceinline__ float block_sum256(float v, float* scratch) {
#pragma unroll
  for (int off = 32; off > 0; off >>= 1) v += __shfl_down(v, off, 64);
  const int wid  = threadIdx.x >> 6;
  const int lane = threadIdx.x & 63;
  __syncthreads();
  if (lane == 0) scratch[wid] = v;
  __syncthreads();
  return scratch[0] + scratch[1] + scratch[2] + scratch[3];
}

// ---- fp32 -> bf16 convert (vectorized x4) ---------------------------------
__global__ __launch_bounds__(256) void f2bf_kernel(const float* __restrict__ in,
                                                   unsigned short* __restrict__ out,
                                                   int n4) {
  const int i = blockIdx.x * 256 + threadIdx.x;
  if (i < n4) {
    const float4 v = ((const float4*)in)[i];
    ushort4 o;
    o.x = f2bf(v.x); o.y = f2bf(v.y); o.z = f2bf(v.z); o.w = f2bf(v.w);
    ((ushort4*)out)[i] = o;
  }
}

// merged per-layer weight conversion: Wq,Wk,Wv,Wo (D*D each) + W1,W2 (F*D each)
// grid: 12288 blocks x 256 (3,145,728 float4 groups total)
__global__ __launch_bounds__(256) void f2bf_layer_kernel(
    const float* __restrict__ wq, const float* __restrict__ wk,
    const float* __restrict__ wv, const float* __restrict__ wo,
    const float* __restrict__ w1, const float* __restrict__ w2,
    unsigned short* __restrict__ dst) {
  const int i = blockIdx.x * 256 + threadIdx.x;   // float4 index
  const float* src;
  size_t so, doff;
  if (i < 1048576) {
    const int seg = i >> 18;          // 0..3
    const int off = i & 262143;
    src = (seg == 0) ? wq : (seg == 1) ? wk : (seg == 2) ? wv : wo;
    so = off;
    doff = (size_t)seg * 1048576 + (size_t)off * 4;
  } else {
    const int j = i - 1048576;
    if (j < 1048576) { src = w1; so = j; doff = 4194304 + (size_t)j * 4; }
    else             { src = w2; so = j - 1048576; doff = 8388608 + (size_t)(j - 1048576) * 4; }
  }
  const float4 v = ((const float4*)src)[so];
  ushort4 o;
  o.x = f2bf(v.x); o.y = f2bf(v.y); o.z = f2bf(v.z); o.w = f2bf(v.w);
  *(ushort4*)(dst + doff) = o;
}

// ---- embedding + positional encoding (writes fp32 x and bf16 xb) ----------
__global__ __launch_bounds__(256) void embed_pe_kernel(
    const int* __restrict__ ids, const float* __restrict__ embed,
    float* __restrict__ x, unsigned short* __restrict__ xb) {
  const int row = blockIdx.x;           // b*kS + s
  const int s   = row & (kS - 1);
  const int id  = ids[row];
  const float* erow = embed + (size_t)id * kD;
#pragma unroll
  for (int i = 0; i < kD / 256; ++i) {
    const int d = threadIdx.x + i * 256;
    const int p = d >> 1;
    const float div = expf((float)p * -0.017988946039015984f); // 2*(-ln(1e4)/1024)
    const float ang = (float)s * div;
    const float pe  = (d & 1) ? cosf(ang) : sinf(ang);
    const float v = erow[d] * 32.0f + pe;   // sqrt(1024)=32
    x[(size_t)row * kD + d]  = v;
    xb[(size_t)row * kD + d] = f2bf(v);
  }
}

// ---- bf16 MFMA GEMM core: C[M,N] = A[M,K(range)] @ W[N,K]^T + bias --------
// MODE 0: fp32 row-major out (bias may be null)
// MODE 1: bf16 out in [b][h][s][dk] layout, scaled by oscale (q/k)
// MODE 2: bf16 row-major out with ReLU
// MODE 3: bf16 out in [b][h][dk][s] layout (v transposed)
template <int MODE>
__device__ __forceinline__ void gemm_core(int bm, int bn,
                                          const unsigned short* __restrict__ A,
                                          const unsigned short* __restrict__ W,
                                          const float* __restrict__ bias,
                                          void* __restrict__ Cout,
                                          int M, int N, int K,
                                          int k0begin, int k0end, float oscale) {
  __shared__ __align__(16) unsigned short As[128 * 32];
  __shared__ __align__(16) unsigned short Ws[128 * 32];
  const int t    = threadIdx.x;
  const int lane = t & 63;
  const int w    = t >> 6;
  const int wm   = (w >> 1) * 64;
  const int wn   = (w & 1) * 64;
  const int l15  = lane & 15;
  const int quad = lane >> 4;

  f32x4 acc[4][4] = {};

  for (int k0 = k0begin; k0 < k0end; k0 += 32) {
    __syncthreads();
#pragma unroll
    for (int i = 0; i < 2; ++i) {
      const int e   = i * 256 + t;       // 0..511
      const int row = e >> 2;            // 0..127
      const int kc  = (e & 3) * 8;       // 0,8,16,24
      const int ldsoff = (i * 256 + w * 64) * 8;   // wave-uniform base (shorts)
      llds16(A + (size_t)(bm + row) * K + k0 + kc, &As[ldsoff]);
      llds16(W + (size_t)(bn + row) * K + k0 + kc, &Ws[ldsoff]);
    }
    __syncthreads();
    short8 af[4], bf[4];
#pragma unroll
    for (int i = 0; i < 4; ++i)
      af[i] = *(const short8*)&As[(wm + i * 16 + l15) * 32 + quad * 8];
#pragma unroll
    for (int j = 0; j < 4; ++j)
      bf[j] = *(const short8*)&Ws[(wn + j * 16 + l15) * 32 + quad * 8];
#pragma unroll
    for (int i = 0; i < 4; ++i)
#pragma unroll
      for (int j = 0; j < 4; ++j)
        acc[i][j] = __builtin_amdgcn_mfma_f32_16x16x32_bf16(af[i], bf[j], acc[i][j], 0, 0, 0);
  }

#pragma unroll
  for (int i = 0; i < 4; ++i) {
#pragma unroll
    for (int r = 0; r < 4; ++r) {
      const int m = bm + wm + i * 16 + quad * 4 + r;
#pragma unroll
      for (int j = 0; j < 4; ++j) {
        const int n = bn + wn + j * 16 + l15;
        float v = acc[i][j][r] + (bias ? bias[n] : 0.0f);
        if (MODE == 2) v = fmaxf(v, 0.0f);
        if (MODE == 0) {
          ((float*)Cout)[(size_t)m * N + n] = v;
        } else if (MODE == 1) {
          const int b = m >> 10, s = m & 1023;
          const int h = n >> 6,  dk = n & 63;
          ((unsigned short*)Cout)[((size_t)(b * kH + h) * kS + s) * kDK + dk] = f2bf(v * oscale);
        } else if (MODE == 3) {
          const int b = m >> 10, s = m & 1023;
          const int h = n >> 6,  dk = n & 63;
          ((unsigned short*)Cout)[((size_t)(b * kH + h) * kDK + dk) * kS + s] = f2bf(v);
        } else {
          ((unsigned short*)Cout)[(size_t)m * N + n] = f2bf(v);
        }
      }
    }
  }
}

// head GEMM: XCD-chunked bijective swizzle (4000 = 8 XCDs x 500) so the 16
// M-blocks sharing a W-tile run consecutively on ONE XCD's L2; M-fast within.
__global__ __launch_bounds__(256) void gemm_head_kernel(
    const unsigned short* __restrict__ A, const unsigned short* __restrict__ W,
    float* __restrict__ C) {
  const int bid = blockIdx.x;               // 0..3999
  const int wg  = (bid & 7) * 500 + (bid >> 3);   // XCD (bid%8) gets [xcd*500, ...)
  const int bm  = (wg & 15) * 128;          // M fast axis (16 tiles)
  const int bn  = (wg >> 4) * 128;          // 250 N tiles
  gemm_core<0>(bm, bn, A, W, nullptr, C, kM, kV, kD, 0, kD, 1.0f);
}

// fused QKV: z slice picks {Wq->q[bhsd], Wk->k[bhsd], Wv->v[bhds]}
__global__ __launch_bounds__(256) void gemm_qkv_kernel(
    const unsigned short* __restrict__ A,
    const unsigned short* __restrict__ wq, const unsigned short* __restrict__ wk,
    const unsigned short* __restrict__ wv,
    const float* __restrict__ bq_, const float* __restrict__ bk_,
    const float* __restrict__ bv_,
    unsigned short* __restrict__ qo, unsigned short* __restrict__ ko,
    unsigned short* __restrict__ vo) {
  const int bm = blockIdx.y * 128;
  const int bn = blockIdx.x * 128;
  const int z  = blockIdx.z;
  if (z == 0) {
    gemm_core<1>(bm, bn, A, wq, bq_, qo, kM, kD, kD, 0, kD, kScale);
  } else if (z == 1) {
    gemm_core<1>(bm, bn, A, wk, bk_, ko, kM, kD, kD, 0, kD, 1.0f);
  } else {
    gemm_core<3>(bm, bn, A, wv, bv_, vo, kM, kD, kD, 0, kD, 1.0f);
  }
}

// split-K=2 fp32 GEMM: z=0 -> [0,K/2) + bias into C0; z=1 -> [K/2,K) into C1
__global__ __launch_bounds__(256) void gemm_splitk_kernel(
    const unsigned short* __restrict__ A, const unsigned short* __restrict__ W,
    const float* __restrict__ bias, float* __restrict__ C0,
    float* __restrict__ C1, int M, int N, int K) {
  const int bm = blockIdx.y * 128;
  const int bn = blockIdx.x * 128;
  if (blockIdx.z == 0)
    gemm_core<0>(bm, bn, A, W, bias, C0, M, N, K, 0, K / 2, 1.0f);
  else
    gemm_core<0>(bm, bn, A, W, nullptr, C1, M, N, K, K / 2, K, 1.0f);
}

__global__ __launch_bounds__(256) void gemm_bf16relu_kernel(
    const unsigned short* __restrict__ A, const unsigned short* __restrict__ W,
    const float* __restrict__ bias, unsigned short* __restrict__ C,
    int M, int N, int K) {
  gemm_core<2>(blockIdx.y * 128, blockIdx.x * 128, A, W, bias, C, M, N, K, 0, K, 1.0f);
}

// ---- MFMA flash attention, barrier-free ------------------------------------
// q (pre-scaled), k: bf16 [b][h][s][dk]; vt: bf16 [b][h][dk][s]
// out ob: bf16 row-major [b*s][D].
// K/V per head = 256 KB -> L1/L2-resident; MFMA fragments load DIRECTLY from
// global (16 B/lane), no LDS staging, no __syncthreads. LDS only holds the
// wave-local P re-fragmentation buffer. XCD swizzle clusters the 16 q-tiles
// of each (b,h) onto one XCD (KV working set 1 MB < 4 MB L2).
__global__ __launch_bounds__(256) void attn_mfma_kernel(
    const unsigned short* __restrict__ q, const unsigned short* __restrict__ k,
    const unsigned short* __restrict__ vt, unsigned short* __restrict__ ob) {
  const int bid = blockIdx.x;                      // 0..511
  const int wg  = (bid & 7) * 64 + (bid >> 3);     // XCD-chunked bijective
  const int qt  = wg & 15;
  const int h   = (wg >> 4) & 15;
  const int b   = wg >> 8;
  const int q0  = qt * 64;

  __shared__ __align__(16) unsigned short Ps[4][16 * 64];

  const int t    = threadIdx.x;
  const int lane = t & 63;
  const int w    = t >> 6;
  const int l15  = lane & 15;
  const int quad = lane >> 4;

  const size_t base = (size_t)(b * kH + h) * kS * kDK;   // elements (same for k and vt)

  // Q A-fragments for this wave's 16-row strip, direct from global
  short8 aq[2];
#pragma unroll
  for (int ks = 0; ks < 2; ++ks)
    aq[ks] = *(const short8*)(q + base + (size_t)(q0 + w * 16 + l15) * kDK + ks * 32 + quad * 8);

  f32x4 acc_o[4] = {};                     // [dk-tile]: row=quad*4+r, dk=jd*16+l15
  float m[4]    = {-1e30f, -1e30f, -1e30f, -1e30f};
  float lsum[4] = {0.f, 0.f, 0.f, 0.f};

  for (int kt = 0; kt <= qt; ++kt) {
    // ---- S = Q @ K^T for this wave's 16x64 strip (K frags direct) ----------
    f32x4 s[4] = {};
#pragma unroll
    for (int j = 0; j < 4; ++j) {
#pragma unroll
      for (int ks = 0; ks < 2; ++ks) {
        const short8 bk8 = *(const short8*)(k + base +
            (size_t)(kt * 64 + j * 16 + l15) * kDK + ks * 32 + quad * 8);
        s[j] = __builtin_amdgcn_mfma_f32_16x16x32_bf16(aq[ks], bk8, s[j], 0, 0, 0);
      }
    }

    // causal mask (diagonal tile only): key j*16+l15 > query w*16+quad*4+r
    if (kt == qt) {
      const int rb = w * 16 + quad * 4;
#pragma unroll
      for (int j = 0; j < 4; ++j) {
        const int kg = j * 16 + l15;
#pragma unroll
        for (int r = 0; r < 4; ++r)
          if (kg > rb + r) s[j][r] = -1e30f;
      }
    }

    // ---- online softmax (rows spread over 16-lane groups) ------------------
    float pm[4];
#pragma unroll
    for (int r = 0; r < 4; ++r)
      pm[r] = fmaxf(fmaxf(s[0][r], s[1][r]), fmaxf(s[2][r], s[3][r]));
#pragma unroll
    for (int off = 8; off > 0; off >>= 1)
#pragma unroll
      for (int r = 0; r < 4; ++r)
        pm[r] = fmaxf(pm[r], __shfl_xor(pm[r], off, 64));

    float alpha[4];
#pragma unroll
    for (int r = 0; r < 4; ++r) {
      const float mn = fmaxf(m[r], pm[r]);
      alpha[r] = __expf(m[r] - mn);
      m[r] = mn;
    }

    float rs[4] = {0.f, 0.f, 0.f, 0.f};
    unsigned short pb16[4][4];
#pragma unroll
    for (int j = 0; j < 4; ++j)
#pragma unroll
      for (int r = 0; r < 4; ++r) {
        const float e = __expf(s[j][r] - m[r]);
        rs[r] += e;
        pb16[j][r] = f2bf(e);
      }
#pragma unroll
    for (int off = 8; off > 0; off >>= 1)
#pragma unroll
      for (int r = 0; r < 4; ++r)
        rs[r] += __shfl_xor(rs[r], off, 64);
#pragma unroll
    for (int r = 0; r < 4; ++r) lsum[r] = lsum[r] * alpha[r] + rs[r];
#pragma unroll
    for (int jd = 0; jd < 4; ++jd)
#pragma unroll
      for (int r = 0; r < 4; ++r) acc_o[jd][r] *= alpha[r];

    // ---- P -> LDS (wave-local region, swizzled), re-fragment for PV --------
#pragma unroll
    for (int j = 0; j < 4; ++j)
#pragma unroll
      for (int r = 0; r < 4; ++r) {
        const int row = quad * 4 + r;
        const int col = j * 16 + l15;
        Ps[w][row * 64 + (((col >> 3) ^ (row & 7)) << 3) + (col & 7)] = pb16[j][r];
      }
    asm volatile("s_waitcnt lgkmcnt(0)" ::: "memory");
    __builtin_amdgcn_sched_barrier(0);

    short8 ap[2];
#pragma unroll
    for (int ks = 0; ks < 2; ++ks)
      ap[ks] = *(const short8*)&Ps[w][l15 * 64 + (((ks * 4 + quad) ^ (l15 & 7)) * 8)];

    // ---- O += P @ V (V^T frags direct from global) -------------------------
#pragma unroll
    for (int jd = 0; jd < 4; ++jd) {
#pragma unroll
      for (int ks = 0; ks < 2; ++ks) {
        const short8 bv8 = *(const short8*)(vt + base +
            (size_t)(jd * 16 + l15) * kS + kt * 64 + ks * 32 + quad * 8);
        acc_o[jd] = __builtin_amdgcn_mfma_f32_16x16x32_bf16(ap[ks], bv8, acc_o[jd], 0, 0, 0);
      }
    }
  }

  // ---- epilogue: normalize and write bf16 [b*s][D] --------------------------
  float inv[4];
#pragma unroll
  for (int r = 0; r < 4; ++r) inv[r] = 1.0f / lsum[r];
#pragma unroll
  for (int jd = 0; jd < 4; ++jd)
#pragma unroll
    for (int r = 0; r < 4; ++r) {
      const int qg = q0 + w * 16 + quad * 4 + r;
      ob[(size_t)(b * kS + qg) * kD + h * kDK + jd * 16 + l15] =
          f2bf(acc_o[jd][r] * inv[r]);
    }
}

// ---- residual add(s) + LayerNorm; writes fp32 x and bf16 xb ---------------
__global__ __launch_bounds__(256) void add_ln_kernel(
    float* __restrict__ x, const float* __restrict__ res,
    const float* __restrict__ res2,
    const float* __restrict__ g, const float* __restrict__ bta,
    unsigned short* __restrict__ xb) {
  const int row = blockIdx.x;
  const int t   = threadIdx.x;
  __shared__ float scratch[4];
  float vals[4];
  float sum = 0.f;
  float* xrow = x + (size_t)row * kD;
#pragma unroll
  for (int i = 0; i < 4; ++i) {
    const int d = t + i * 256;
    float vv = xrow[d];
    if (res)  vv += res[(size_t)row * kD + d];
    if (res2) vv += res2[(size_t)row * kD + d];
    vals[i] = vv;
    sum += vv;
  }
  const float mean = block_sum256(sum, scratch) * (1.0f / kD);
  float vsum = 0.f;
#pragma unroll
  for (int i = 0; i < 4; ++i) {
    const float dd = vals[i] - mean;
    vsum += dd * dd;
  }
  const float var  = block_sum256(vsum, scratch) * (1.0f / kD);
  const float rstd = rsqrtf(var + kEps);
#pragma unroll
  for (int i = 0; i < 4; ++i) {
    const int d = t + i * 256;
    const float o = (vals[i] - mean) * rstd * g[d] + bta[d];
    xrow[d] = o;
    xb[(size_t)row * kD + d] = f2bf(o);
  }
}

// ---------------------------------------------------------------------------
extern "C" void kernel_launch(void* const* d_in, const int* in_sizes, int n_in,
                              void* d_out, int out_size, void* d_ws, size_t ws_size,
                              hipStream_t stream) {
  const int*   ids   = (const int*)  d_in[0];
  const float* embed = (const float*)d_in[1];
  const float* Wq    = (const float*)d_in[2];
  const float* bq    = (const float*)d_in[3];
  const float* Wk    = (const float*)d_in[4];
  const float* bk    = (const float*)d_in[5];
  const float* Wv    = (const float*)d_in[6];
  const float* bv    = (const float*)d_in[7];
  const float* Wo    = (const float*)d_in[8];
  const float* bo    = (const float*)d_in[9];
  const float* ln1g  = (const float*)d_in[10];
  const float* ln1b  = (const float*)d_in[11];
  const float* W1    = (const float*)d_in[12];
  const float* b1    = (const float*)d_in[13];
  const float* W2    = (const float*)d_in[14];
  const float* b2    = (const float*)d_in[15];
  const float* ln2g  = (const float*)d_in[16];
  const float* ln2b  = (const float*)d_in[17];
  const float* lnfg  = (const float*)d_in[18];
  const float* lnfb  = (const float*)d_in[19];
  const float* headw = (const float*)d_in[20];

  // Workspace layout (bytes):
  char* ws = (char*)d_ws;
  float*          x    = (float*)          (ws);              // 8 MB fp32 [M][D]
  unsigned short* xb   = (unsigned short*) (ws + 8388608);    // 4 MB bf16 [M][D]
  unsigned short* qbb  = (unsigned short*) (ws + 12582912);   // 4 MB bf16 [b][h][s][dk] (pre-scaled)
  unsigned short* kbb  = (unsigned short*) (ws + 16777216);   // 4 MB bf16 [b][h][s][dk]
  unsigned short* vtb  = (unsigned short*) (ws + 20971520);   // 4 MB bf16 [b][h][dk][s]
  unsigned short* ob   = (unsigned short*) (ws + 25165824);   // 4 MB bf16 [M][D]
  unsigned short* ff1b = (unsigned short*) (ws + 29360128);   // 16 MB bf16 [M][F]
  float*          pb   = (float*)          (ws + 46137344);   // 8 MB fp32 [M][D]
  float*          pb2  = (float*)          (ws + 54525952);   // 8 MB fp32 [M][D]
  unsigned short* wbuf = (unsigned short*) (ws + 67108864);   // bf16 weights
  // wbuf element offsets: wq 0, wk 1M, wv 2M, wo 3M, w1 4M..8M, w2 8M..12M
  // head reuses wbuf[0 .. 32.768M)

  const dim3 blk(256);
  embed_pe_kernel<<<kM, blk, 0, stream>>>(ids, embed, x, xb);

  for (int l = 0; l < kL; ++l) {
    const size_t oD = (size_t)l * kD * kD;     // 1M
    const size_t oF = (size_t)l * kF * kD;     // 4M
    // convert this layer's weights to bf16 (single merged launch)
    f2bf_layer_kernel<<<12288, blk, 0, stream>>>(
        Wq + oD, Wk + oD, Wv + oD, Wo + oD, W1 + oF, W2 + oF, wbuf);

    gemm_qkv_kernel<<<dim3(8, 16, 3), blk, 0, stream>>>(
        xb, wbuf, wbuf + 1048576, wbuf + 2097152,
        bq + (size_t)l * kD, bk + (size_t)l * kD, bv + (size_t)l * kD,
        qbb, kbb, vtb);
    attn_mfma_kernel<<<kB * kH * (kS / 64), blk, 0, stream>>>(qbb, kbb, vtb, ob);
    gemm_splitk_kernel<<<dim3(8, 16, 2), blk, 0, stream>>>(
        ob, wbuf + 3145728, bo + (size_t)l * kD, pb, pb2, kM, kD, kD);
    add_ln_kernel<<<kM, blk, 0, stream>>>(
        x, pb, pb2, ln1g + (size_t)l * kD, ln1b + (size_t)l * kD, xb);
    gemm_bf16relu_kernel<<<dim3(32, 16), blk, 0, stream>>>(
        xb, wbuf + 4194304, b1 + (size_t)l * kF, ff1b, kM, kF, kD);
    gemm_splitk_kernel<<<dim3(8, 16, 2), blk, 0, stream>>>(
        ff1b, wbuf + 8388608, b2 + (size_t)l * kD, pb, pb2, kM, kD, kF);
    add_ln_kernel<<<kM, blk, 0, stream>>>(
        x, pb, pb2, ln2g + (size_t)l * kD, ln2b + (size_t)l * kD, xb);
  }

  add_ln_kernel<<<kM, blk, 0, stream>>>(x, nullptr, nullptr, lnfg, lnfb, xb);
  f2bf_kernel<<<32000, blk, 0, stream>>>(headw, wbuf, 8192000);
  gemm_head_kernel<<<dim3(4000), blk, 0, stream>>>(xb, wbuf, (float*)d_out);
}

// Round 4
// 1532.757 us; speedup vs baseline: 1.0772x; 1.0772x over previous
//
#include <hip/hip_runtime.h>
#include <math.h>

// ---------------------------------------------------------------------------
// Round 6: revert r5's regressions (barrier-free attn -> staged; fp32 PE ->
// f64 PE for absmax), keep r5's wins (head XCD swizzle, merged f2bf).
// NEW: attention K/V staging is now double-buffered with a single barrier per
// KV tile (T3-minimum 2-phase pipeline): stage(kt+1) issued BEFORE compute(kt)
// so global->LDS latency hides under softmax+MFMA. Q frags direct from global.
// ---------------------------------------------------------------------------

namespace {
constexpr int kV  = 32000;
constexpr int kD  = 1024;
constexpr int kH  = 16;
constexpr int kL  = 4;
constexpr int kF  = 4096;
constexpr int kS  = 1024;
constexpr int kB  = 2;
constexpr int kDK = 64;
constexpr int kM  = kB * kS;   // 2048 rows
constexpr float kEps   = 1e-5f;
constexpr float kScale = 0.125f;   // 1/sqrt(DK)
}

using short8 = __attribute__((ext_vector_type(8))) short;
using f32x4  = __attribute__((ext_vector_type(4))) float;

__device__ __forceinline__ unsigned short f2bf(float f) {
  union { float f; unsigned int u; } x{f};
  const unsigned int r = x.u + 0x7fffu + ((x.u >> 16) & 1u);
  return (unsigned short)(r >> 16);
}

// async 16B global -> LDS (lds base must be wave-uniform; lane scatters +16B)
__device__ __forceinline__ void llds16(const void* g, void* l) {
  __builtin_amdgcn_global_load_lds(
      (const __attribute__((address_space(1))) unsigned int*)g,
      (__attribute__((address_space(3))) unsigned int*)l, 16, 0, 0);
}

// ---- block reductions (blockDim.x == 256 -> 4 waves of 64) ----------------
__device__ __forceinline__ float block_sum256(float v, float* scratch) {
#pragma unroll
  for (int off = 32; off > 0; off >>= 1) v += __shfl_down(v, off, 64);
  const int wid  = threadIdx.x >> 6;
  const int lane = threadIdx.x & 63;
  __syncthreads();
  if (lane == 0) scratch[wid] = v;
  __syncthreads();
  return scratch[0] + scratch[1] + scratch[2] + scratch[3];
}

// ---- fp32 -> bf16 convert (vectorized x4) ---------------------------------
__global__ __launch_bounds__(256) void f2bf_kernel(const float* __restrict__ in,
                                                   unsigned short* __restrict__ out,
                                                   int n4) {
  const int i = blockIdx.x * 256 + threadIdx.x;
  if (i < n4) {
    const float4 v = ((const float4*)in)[i];
    ushort4 o;
    o.x = f2bf(v.x); o.y = f2bf(v.y); o.z = f2bf(v.z); o.w = f2bf(v.w);
    ((ushort4*)out)[i] = o;
  }
}

// merged per-layer weight conversion: Wq,Wk,Wv,Wo (D*D each) + W1,W2 (F*D each)
// grid: 12288 blocks x 256 (3,145,728 float4 groups total)
__global__ __launch_bounds__(256) void f2bf_layer_kernel(
    const float* __restrict__ wq, const float* __restrict__ wk,
    const float* __restrict__ wv, const float* __restrict__ wo,
    const float* __restrict__ w1, const float* __restrict__ w2,
    unsigned short* __restrict__ dst) {
  const int i = blockIdx.x * 256 + threadIdx.x;   // float4 index
  const float* src;
  size_t so, doff;
  if (i < 1048576) {
    const int seg = i >> 18;          // 0..3
    const int off = i & 262143;
    src = (seg == 0) ? wq : (seg == 1) ? wk : (seg == 2) ? wv : wo;
    so = off;
    doff = (size_t)seg * 1048576 + (size_t)off * 4;
  } else {
    const int j = i - 1048576;
    if (j < 1048576) { src = w1; so = j; doff = 4194304 + (size_t)j * 4; }
    else             { src = w2; so = j - 1048576; doff = 8388608 + (size_t)(j - 1048576) * 4; }
  }
  const float4 v = ((const float4*)src)[so];
  ushort4 o;
  o.x = f2bf(v.x); o.y = f2bf(v.y); o.z = f2bf(v.z); o.w = f2bf(v.w);
  *(ushort4*)(dst + doff) = o;
}

// ---- embedding + positional encoding (writes fp32 x and bf16 xb) ----------
// f64 PE trig: matches the jnp.float32 reference closely enough to keep the
// end-to-end absmax at 0.0156 (fp32 trig regressed it to 0.0195).
__global__ __launch_bounds__(256) void embed_pe_kernel(
    const int* __restrict__ ids, const float* __restrict__ embed,
    float* __restrict__ x, unsigned short* __restrict__ xb) {
  const int row = blockIdx.x;           // b*kS + s
  const int s   = row & (kS - 1);
  const int id  = ids[row];
  const float* erow = embed + (size_t)id * kD;
#pragma unroll
  for (int i = 0; i < kD / 256; ++i) {
    const int d = threadIdx.x + i * 256;
    const int p = d >> 1;
    const double div = exp((double)(2 * p) * (-9.210340371976184 / 1024.0));
    const double ang = (double)s * div;
    const float pe = (d & 1) ? (float)cos(ang) : (float)sin(ang);
    const float v = erow[d] * 32.0f + pe;   // sqrt(1024)=32
    x[(size_t)row * kD + d]  = v;
    xb[(size_t)row * kD + d] = f2bf(v);
  }
}

// ---- bf16 MFMA GEMM core: C[M,N] = A[M,K(range)] @ W[N,K]^T + bias --------
// MODE 0: fp32 row-major out (bias may be null)
// MODE 1: bf16 out in [b][h][s][dk] layout, scaled by oscale (q/k)
// MODE 2: bf16 row-major out with ReLU
// MODE 3: bf16 out in [b][h][dk][s] layout (v transposed)
template <int MODE>
__device__ __forceinline__ void gemm_core(int bm, int bn,
                                          const unsigned short* __restrict__ A,
                                          const unsigned short* __restrict__ W,
                                          const float* __restrict__ bias,
                                          void* __restrict__ Cout,
                                          int M, int N, int K,
                                          int k0begin, int k0end, float oscale) {
  __shared__ __align__(16) unsigned short As[128 * 32];
  __shared__ __align__(16) unsigned short Ws[128 * 32];
  const int t    = threadIdx.x;
  const int lane = t & 63;
  const int w    = t >> 6;
  const int wm   = (w >> 1) * 64;
  const int wn   = (w & 1) * 64;
  const int l15  = lane & 15;
  const int quad = lane >> 4;

  f32x4 acc[4][4] = {};

  for (int k0 = k0begin; k0 < k0end; k0 += 32) {
    __syncthreads();
#pragma unroll
    for (int i = 0; i < 2; ++i) {
      const int e   = i * 256 + t;       // 0..511
      const int row = e >> 2;            // 0..127
      const int kc  = (e & 3) * 8;       // 0,8,16,24
      const int ldsoff = (i * 256 + w * 64) * 8;   // wave-uniform base (shorts)
      llds16(A + (size_t)(bm + row) * K + k0 + kc, &As[ldsoff]);
      llds16(W + (size_t)(bn + row) * K + k0 + kc, &Ws[ldsoff]);
    }
    __syncthreads();
    short8 af[4], bf[4];
#pragma unroll
    for (int i = 0; i < 4; ++i)
      af[i] = *(const short8*)&As[(wm + i * 16 + l15) * 32 + quad * 8];
#pragma unroll
    for (int j = 0; j < 4; ++j)
      bf[j] = *(const short8*)&Ws[(wn + j * 16 + l15) * 32 + quad * 8];
#pragma unroll
    for (int i = 0; i < 4; ++i)
#pragma unroll
      for (int j = 0; j < 4; ++j)
        acc[i][j] = __builtin_amdgcn_mfma_f32_16x16x32_bf16(af[i], bf[j], acc[i][j], 0, 0, 0);
  }

#pragma unroll
  for (int i = 0; i < 4; ++i) {
#pragma unroll
    for (int r = 0; r < 4; ++r) {
      const int m = bm + wm + i * 16 + quad * 4 + r;
#pragma unroll
      for (int j = 0; j < 4; ++j) {
        const int n = bn + wn + j * 16 + l15;
        float v = acc[i][j][r] + (bias ? bias[n] : 0.0f);
        if (MODE == 2) v = fmaxf(v, 0.0f);
        if (MODE == 0) {
          ((float*)Cout)[(size_t)m * N + n] = v;
        } else if (MODE == 1) {
          const int b = m >> 10, s = m & 1023;
          const int h = n >> 6,  dk = n & 63;
          ((unsigned short*)Cout)[((size_t)(b * kH + h) * kS + s) * kDK + dk] = f2bf(v * oscale);
        } else if (MODE == 3) {
          const int b = m >> 10, s = m & 1023;
          const int h = n >> 6,  dk = n & 63;
          ((unsigned short*)Cout)[((size_t)(b * kH + h) * kDK + dk) * kS + s] = f2bf(v);
        } else {
          ((unsigned short*)Cout)[(size_t)m * N + n] = f2bf(v);
        }
      }
    }
  }
}

// head GEMM: XCD-chunked bijective swizzle (4000 = 8 XCDs x 500) so the 16
// M-blocks sharing a W-tile run consecutively on ONE XCD's L2; M-fast within.
__global__ __launch_bounds__(256) void gemm_head_kernel(
    const unsigned short* __restrict__ A, const unsigned short* __restrict__ W,
    float* __restrict__ C) {
  const int bid = blockIdx.x;               // 0..3999
  const int wg  = (bid & 7) * 500 + (bid >> 3);   // XCD (bid%8) gets [xcd*500, ...)
  const int bm  = (wg & 15) * 128;          // M fast axis (16 tiles)
  const int bn  = (wg >> 4) * 128;          // 250 N tiles
  gemm_core<0>(bm, bn, A, W, nullptr, C, kM, kV, kD, 0, kD, 1.0f);
}

// fused QKV: z slice picks {Wq->q[bhsd], Wk->k[bhsd], Wv->v[bhds]}
__global__ __launch_bounds__(256) void gemm_qkv_kernel(
    const unsigned short* __restrict__ A,
    const unsigned short* __restrict__ wq, const unsigned short* __restrict__ wk,
    const unsigned short* __restrict__ wv,
    const float* __restrict__ bq_, const float* __restrict__ bk_,
    const float* __restrict__ bv_,
    unsigned short* __restrict__ qo, unsigned short* __restrict__ ko,
    unsigned short* __restrict__ vo) {
  const int bm = blockIdx.y * 128;
  const int bn = blockIdx.x * 128;
  const int z  = blockIdx.z;
  if (z == 0) {
    gemm_core<1>(bm, bn, A, wq, bq_, qo, kM, kD, kD, 0, kD, kScale);
  } else if (z == 1) {
    gemm_core<1>(bm, bn, A, wk, bk_, ko, kM, kD, kD, 0, kD, 1.0f);
  } else {
    gemm_core<3>(bm, bn, A, wv, bv_, vo, kM, kD, kD, 0, kD, 1.0f);
  }
}

// split-K=2 fp32 GEMM: z=0 -> [0,K/2) + bias into C0; z=1 -> [K/2,K) into C1
__global__ __launch_bounds__(256) void gemm_splitk_kernel(
    const unsigned short* __restrict__ A, const unsigned short* __restrict__ W,
    const float* __restrict__ bias, float* __restrict__ C0,
    float* __restrict__ C1, int M, int N, int K) {
  const int bm = blockIdx.y * 128;
  const int bn = blockIdx.x * 128;
  if (blockIdx.z == 0)
    gemm_core<0>(bm, bn, A, W, bias, C0, M, N, K, 0, K / 2, 1.0f);
  else
    gemm_core<0>(bm, bn, A, W, nullptr, C1, M, N, K, K / 2, K, 1.0f);
}

__global__ __launch_bounds__(256) void gemm_bf16relu_kernel(
    const unsigned short* __restrict__ A, const unsigned short* __restrict__ W,
    const float* __restrict__ bias, unsigned short* __restrict__ C,
    int M, int N, int K) {
  gemm_core<2>(blockIdx.y * 128, blockIdx.x * 128, A, W, bias, C, M, N, K, 0, K, 1.0f);
}

// ---- MFMA flash attention, double-buffered staging (1 barrier / KV tile) ---
// q (pre-scaled), k: bf16 [b][h][s][dk]; vt: bf16 [b][h][dk][s]
// out ob: bf16 row-major [b*s][D].
// Block = (b, h, 64-query tile); 4 waves x 16-row strips. K/V tiles staged in
// LDS (XOR-swizzled via pre-swizzled global source); stage(kt+1) issued before
// compute(kt) so the global->LDS DMA hides under softmax+MFMA; the single
// end-of-iter __syncthreads (compiler drains vmcnt there) publishes the buffer.
__global__ __launch_bounds__(256) void attn_mfma_kernel(
    const unsigned short* __restrict__ q, const unsigned short* __restrict__ k,
    const unsigned short* __restrict__ vt, unsigned short* __restrict__ ob) {
  const int bid = blockIdx.x;                      // 0..511
  const int wg  = (bid & 7) * 64 + (bid >> 3);     // XCD-chunked bijective
  const int qt  = wg & 15;
  const int h   = (wg >> 4) & 15;
  const int b   = wg >> 8;
  const int q0  = qt * 64;

  __shared__ __align__(16) unsigned short Ks[2][64 * 64];
  __shared__ __align__(16) unsigned short Vs[2][64 * 64];   // [dk][key]
  __shared__ __align__(16) unsigned short Ps[4][16 * 64];

  const int t    = threadIdx.x;
  const int lane = t & 63;
  const int w    = t >> 6;
  const int l15  = lane & 15;
  const int quad = lane >> 4;

  const size_t base = (size_t)(b * kH + h) * kS * kDK;   // elements (k and vt)

  // stage KV tile kt_ into buffer buf (source pre-swizzled, LDS linear)
  auto stage = [&](int kt_, int buf) {
#pragma unroll
    for (int i = 0; i < 2; ++i) {
      const int e   = i * 256 + t;
      const int row = e >> 3;
      const int g   = e & 7;
      llds16(k + base + (size_t)(kt_ * 64 + row) * kDK + ((g ^ (row & 7)) * 8),
             &Ks[buf][(i * 256 + w * 64) * 8]);
      llds16(vt + base + (size_t)row * kS + kt_ * 64 + ((g ^ (row & 7)) * 8),
             &Vs[buf][(i * 256 + w * 64) * 8]);
    }
  };

  // Q A-fragments for this wave's 16-row strip, direct from global (once)
  short8 aq[2];
#pragma unroll
  for (int ks = 0; ks < 2; ++ks)
    aq[ks] = *(const short8*)(q + base + (size_t)(q0 + w * 16 + l15) * kDK + ks * 32 + quad * 8);

  f32x4 acc_o[4] = {};                     // [dk-tile]: row=quad*4+r, dk=jd*16+l15
  float m[4]    = {-1e30f, -1e30f, -1e30f, -1e30f};
  float lsum[4] = {0.f, 0.f, 0.f, 0.f};

  stage(0, 0);
  __syncthreads();                         // drains vmcnt: tile 0 staged

  for (int kt = 0; kt <= qt; ++kt) {
    const int cur = kt & 1;
    if (kt < qt) stage(kt + 1, cur ^ 1);   // issue next tile's DMA early

    // ---- S = Q @ K^T for this wave's 16x64 strip ---------------------------
    f32x4 s[4] = {};
#pragma unroll
    for (int j = 0; j < 4; ++j) {
#pragma unroll
      for (int ks = 0; ks < 2; ++ks) {
        const short8 bk8 = *(const short8*)&Ks[cur][(j * 16 + l15) * 64 +
                                                   (((ks * 4 + quad) ^ (l15 & 7)) * 8)];
        s[j] = __builtin_amdgcn_mfma_f32_16x16x32_bf16(aq[ks], bk8, s[j], 0, 0, 0);
      }
    }

    // causal mask (diagonal tile only): key j*16+l15 > query w*16+quad*4+r
    if (kt == qt) {
      const int rb = w * 16 + quad * 4;
#pragma unroll
      for (int j = 0; j < 4; ++j) {
        const int kg = j * 16 + l15;
#pragma unroll
        for (int r = 0; r < 4; ++r)
          if (kg > rb + r) s[j][r] = -1e30f;
      }
    }

    // ---- online softmax (rows spread over 16-lane groups) ------------------
    float pm[4];
#pragma unroll
    for (int r = 0; r < 4; ++r)
      pm[r] = fmaxf(fmaxf(s[0][r], s[1][r]), fmaxf(s[2][r], s[3][r]));
#pragma unroll
    for (int off = 8; off > 0; off >>= 1)
#pragma unroll
      for (int r = 0; r < 4; ++r)
        pm[r] = fmaxf(pm[r], __shfl_xor(pm[r], off, 64));

    float alpha[4];
#pragma unroll
    for (int r = 0; r < 4; ++r) {
      const float mn = fmaxf(m[r], pm[r]);
      alpha[r] = __expf(m[r] - mn);
      m[r] = mn;
    }

    float rs[4] = {0.f, 0.f, 0.f, 0.f};
    unsigned short pb16[4][4];
#pragma unroll
    for (int j = 0; j < 4; ++j)
#pragma unroll
      for (int r = 0; r < 4; ++r) {
        const float e = __expf(s[j][r] - m[r]);
        rs[r] += e;
        pb16[j][r] = f2bf(e);
      }
#pragma unroll
    for (int off = 8; off > 0; off >>= 1)
#pragma unroll
      for (int r = 0; r < 4; ++r)
        rs[r] += __shfl_xor(rs[r], off, 64);
#pragma unroll
    for (int r = 0; r < 4; ++r) lsum[r] = lsum[r] * alpha[r] + rs[r];
#pragma unroll
    for (int jd = 0; jd < 4; ++jd)
#pragma unroll
      for (int r = 0; r < 4; ++r) acc_o[jd][r] *= alpha[r];

    // ---- P -> LDS (wave-local region, swizzled), re-fragment for PV --------
#pragma unroll
    for (int j = 0; j < 4; ++j)
#pragma unroll
      for (int r = 0; r < 4; ++r) {
        const int row = quad * 4 + r;
        const int col = j * 16 + l15;
        Ps[w][row * 64 + (((col >> 3) ^ (row & 7)) << 3) + (col & 7)] = pb16[j][r];
      }
    asm volatile("s_waitcnt lgkmcnt(0)" ::: "memory");
    __builtin_amdgcn_sched_barrier(0);

    short8 ap[2];
#pragma unroll
    for (int ks = 0; ks < 2; ++ks)
      ap[ks] = *(const short8*)&Ps[w][l15 * 64 + (((ks * 4 + quad) ^ (l15 & 7)) * 8)];

    // ---- O += P @ V (V^T tile gives B-fragments directly) ------------------
#pragma unroll
    for (int jd = 0; jd < 4; ++jd) {
#pragma unroll
      for (int ks = 0; ks < 2; ++ks) {
        const short8 bv8 = *(const short8*)&Vs[cur][(jd * 16 + l15) * 64 +
                                                   (((ks * 4 + quad) ^ (l15 & 7)) * 8)];
        acc_o[jd] = __builtin_amdgcn_mfma_f32_16x16x32_bf16(ap[ks], bv8, acc_o[jd], 0, 0, 0);
      }
    }

    __syncthreads();   // drains vmcnt (next buffer staged) + retires this buf
  }

  // ---- epilogue: normalize and write bf16 [b*s][D] --------------------------
  float inv[4];
#pragma unroll
  for (int r = 0; r < 4; ++r) inv[r] = 1.0f / lsum[r];
#pragma unroll
  for (int jd = 0; jd < 4; ++jd)
#pragma unroll
    for (int r = 0; r < 4; ++r) {
      const int qg = q0 + w * 16 + quad * 4 + r;
      ob[(size_t)(b * kS + qg) * kD + h * kDK + jd * 16 + l15] =
          f2bf(acc_o[jd][r] * inv[r]);
    }
}

// ---- residual add(s) + LayerNorm; writes fp32 x and bf16 xb ---------------
__global__ __launch_bounds__(256) void add_ln_kernel(
    float* __restrict__ x, const float* __restrict__ res,
    const float* __restrict__ res2,
    const float* __restrict__ g, const float* __restrict__ bta,
    unsigned short* __restrict__ xb) {
  const int row = blockIdx.x;
  const int t   = threadIdx.x;
  __shared__ float scratch[4];
  float vals[4];
  float sum = 0.f;
  float* xrow = x + (size_t)row * kD;
#pragma unroll
  for (int i = 0; i < 4; ++i) {
    const int d = t + i * 256;
    float vv = xrow[d];
    if (res)  vv += res[(size_t)row * kD + d];
    if (res2) vv += res2[(size_t)row * kD + d];
    vals[i] = vv;
    sum += vv;
  }
  const float mean = block_sum256(sum, scratch) * (1.0f / kD);
  float vsum = 0.f;
#pragma unroll
  for (int i = 0; i < 4; ++i) {
    const float dd = vals[i] - mean;
    vsum += dd * dd;
  }
  const float var  = block_sum256(vsum, scratch) * (1.0f / kD);
  const float rstd = rsqrtf(var + kEps);
#pragma unroll
  for (int i = 0; i < 4; ++i) {
    const int d = t + i * 256;
    const float o = (vals[i] - mean) * rstd * g[d] + bta[d];
    xrow[d] = o;
    xb[(size_t)row * kD + d] = f2bf(o);
  }
}

// ---------------------------------------------------------------------------
extern "C" void kernel_launch(void* const* d_in, const int* in_sizes, int n_in,
                              void* d_out, int out_size, void* d_ws, size_t ws_size,
                              hipStream_t stream) {
  const int*   ids   = (const int*)  d_in[0];
  const float* embed = (const float*)d_in[1];
  const float* Wq    = (const float*)d_in[2];
  const float* bq    = (const float*)d_in[3];
  const float* Wk    = (const float*)d_in[4];
  const float* bk    = (const float*)d_in[5];
  const float* Wv    = (const float*)d_in[6];
  const float* bv    = (const float*)d_in[7];
  const float* Wo    = (const float*)d_in[8];
  const float* bo    = (const float*)d_in[9];
  const float* ln1g  = (const float*)d_in[10];
  const float* ln1b  = (const float*)d_in[11];
  const float* W1    = (const float*)d_in[12];
  const float* b1    = (const float*)d_in[13];
  const float* W2    = (const float*)d_in[14];
  const float* b2    = (const float*)d_in[15];
  const float* ln2g  = (const float*)d_in[16];
  const float* ln2b  = (const float*)d_in[17];
  const float* lnfg  = (const float*)d_in[18];
  const float* lnfb  = (const float*)d_in[19];
  const float* headw = (const float*)d_in[20];

  // Workspace layout (bytes):
  char* ws = (char*)d_ws;
  float*          x    = (float*)          (ws);              // 8 MB fp32 [M][D]
  unsigned short* xb   = (unsigned short*) (ws + 8388608);    // 4 MB bf16 [M][D]
  unsigned short* qbb  = (unsigned short*) (ws + 12582912);   // 4 MB bf16 [b][h][s][dk] (pre-scaled)
  unsigned short* kbb  = (unsigned short*) (ws + 16777216);   // 4 MB bf16 [b][h][s][dk]
  unsigned short* vtb  = (unsigned short*) (ws + 20971520);   // 4 MB bf16 [b][h][dk][s]
  unsigned short* ob   = (unsigned short*) (ws + 25165824);   // 4 MB bf16 [M][D]
  unsigned short* ff1b = (unsigned short*) (ws + 29360128);   // 16 MB bf16 [M][F]
  float*          pb   = (float*)          (ws + 46137344);   // 8 MB fp32 [M][D]
  float*          pb2  = (float*)          (ws + 54525952);   // 8 MB fp32 [M][D]
  unsigned short* wbuf = (unsigned short*) (ws + 67108864);   // bf16 weights
  // wbuf element offsets: wq 0, wk 1M, wv 2M, wo 3M, w1 4M..8M, w2 8M..12M
  // head reuses wbuf[0 .. 32.768M)

  const dim3 blk(256);
  embed_pe_kernel<<<kM, blk, 0, stream>>>(ids, embed, x, xb);

  for (int l = 0; l < kL; ++l) {
    const size_t oD = (size_t)l * kD * kD;     // 1M
    const size_t oF = (size_t)l * kF * kD;     // 4M
    // convert this layer's weights to bf16 (single merged launch)
    f2bf_layer_kernel<<<12288, blk, 0, stream>>>(
        Wq + oD, Wk + oD, Wv + oD, Wo + oD, W1 + oF, W2 + oF, wbuf);

    gemm_qkv_kernel<<<dim3(8, 16, 3), blk, 0, stream>>>(
        xb, wbuf, wbuf + 1048576, wbuf + 2097152,
        bq + (size_t)l * kD, bk + (size_t)l * kD, bv + (size_t)l * kD,
        qbb, kbb, vtb);
    attn_mfma_kernel<<<kB * kH * (kS / 64), blk, 0, stream>>>(qbb, kbb, vtb, ob);
    gemm_splitk_kernel<<<dim3(8, 16, 2), blk, 0, stream>>>(
        ob, wbuf + 3145728, bo + (size_t)l * kD, pb, pb2, kM, kD, kD);
    add_ln_kernel<<<kM, blk, 0, stream>>>(
        x, pb, pb2, ln1g + (size_t)l * kD, ln1b + (size_t)l * kD, xb);
    gemm_bf16relu_kernel<<<dim3(32, 16), blk, 0, stream>>>(
        xb, wbuf + 4194304, b1 + (size_t)l * kF, ff1b, kM, kF, kD);
    gemm_splitk_kernel<<<dim3(8, 16, 2), blk, 0, stream>>>(
        ff1b, wbuf + 8388608, b2 + (size_t)l * kD, pb, pb2, kM, kD, kF);
    add_ln_kernel<<<kM, blk, 0, stream>>>(
        x, pb, pb2, ln2g + (size_t)l * kD, ln2b + (size_t)l * kD, xb);
  }

  add_ln_kernel<<<kM, blk, 0, stream>>>(x, nullptr, nullptr, lnfg, lnfb, xb);
  f2bf_kernel<<<32000, blk, 0, stream>>>(headw, wbuf, 8192000);
  gemm_head_kernel<<<dim3(4000), blk, 0, stream>>>(xb, wbuf, (float*)d_out);
}